// Round 1
// baseline (31.614 us; speedup 1.0000x reference)
//
#include <hip/hip_runtime.h>

#define NB   32
#define NT   8192
#define NF   128
#define NOUT 1024
#define SEGSZ 128
#define NSEG  64      // NT / SEGSZ
#define NCHUNK 8      // NOUT / 128

__device__ __forceinline__ float4 f4add(float4 a, float4 b) {
  return make_float4(a.x + b.x, a.y + b.y, a.z + b.z, a.w + b.w);
}
__device__ __forceinline__ float4 f4sub(float4 a, float4 b) {
  return make_float4(a.x - b.x, a.y - b.y, a.z - b.z, a.w - b.w);
}

// Phase 1: S[b][seg][f] = sum over 128 rows of x[b, seg*128 + r, f]
__global__ __launch_bounds__(256) void seg_sums(const float* __restrict__ x,
                                                const int* __restrict__ lengths,
                                                float* __restrict__ S) {
  const int blk = blockIdx.x;       // b * NSEG + seg
  const int b   = blk >> 6;
  const int seg = blk & (NSEG - 1);
  const int len = lengths[b];
  if (seg * SEGSZ >= len) return;   // segment never used (windows end by len)

  const int tid = threadIdx.x;
  const int f4  = tid & 31;         // float4 group within the 128-wide f dim
  const int tl  = tid >> 5;         // 0..7 t-lane

  const float4* xp =
      reinterpret_cast<const float4*>(x + (size_t)b * NT * NF +
                                      (size_t)(seg * SEGSZ) * NF) + f4;
  float4 acc = make_float4(0.f, 0.f, 0.f, 0.f);
  #pragma unroll 4
  for (int r = tl; r < SEGSZ; r += 8)
    acc = f4add(acc, xp[r * 32]);

  __shared__ float4 red[8][32];
  red[tl][f4] = acc;
  __syncthreads();
  if (tl == 0) {
    float4 s = red[0][f4];
    #pragma unroll
    for (int k = 1; k < 8; ++k) s = f4add(s, red[k][f4]);
    reinterpret_cast<float4*>(S + ((size_t)b * NSEG + seg) * NF)[f4] = s;
  }
}

// Phase 2: one block per (b, chunk of 128 outputs).
// A(t) = sum x[b, t : t+W]; out[t] = A(t)/W.
__global__ __launch_bounds__(256) void window_avg(const float* __restrict__ x,
                                                  const int* __restrict__ lengths,
                                                  const float* __restrict__ S,
                                                  float* __restrict__ out) {
  const int blk = blockIdx.x;       // b * NCHUNK + tc
  const int b   = blk >> 3;
  const int tc  = blk & (NCHUNK - 1);
  const int len = lengths[b];
  const int W   = len - NOUT + 1;   // window size (fsize), in [2, 7169]
  const int t0  = tc * 128;         // chunk start (multiple of SEGSZ)
  const int p1  = t0 + W;           // hi cumsum position for t0
  const int s_hi = p1 >> 7;         // segments [tc, s_hi) fully inside window

  const int tid = threadIdx.x;
  const int f4  = tid & 31;
  const int tl  = tid >> 5;         // 0..7, each owns 16 consecutive outputs

  const float4* xb =
      reinterpret_cast<const float4*>(x + (size_t)b * NT * NF) + f4;
  const float4* Sb =
      reinterpret_cast<const float4*>(S + (size_t)b * NSEG * NF) + f4;

  // Cooperative initial window sum A0 = cs[p1] - cs[t0]
  float4 acc = make_float4(0.f, 0.f, 0.f, 0.f);
  for (int s = tc + tl; s < s_hi; s += 8)          // full segments
    acc = f4add(acc, Sb[s * 32]);
  for (int j = (s_hi << 7) + tl; j < p1; j += 8)   // remainder rows
    acc = f4add(acc, xb[j * 32]);

  __shared__ float4 red[8][32];
  red[tl][f4] = acc;
  __syncthreads();
  float4 A = make_float4(0.f, 0.f, 0.f, 0.f);
  #pragma unroll
  for (int k = 0; k < 8; ++k) A = f4add(A, red[k][f4]);
  __syncthreads();

  // Per-t-lane deltas: D[k] = sum_{j<16} (x[p1+16k+j] - x[t0+16k+j]);
  // lane 7's D is never consumed (and would read x[.., 8192] OOB) -> skip.
  float4 D = make_float4(0.f, 0.f, 0.f, 0.f);
  if (tl < 7) {
    const int baseLo = t0 + 16 * tl;
    const int baseHi = p1 + 16 * tl;
    #pragma unroll 4
    for (int j = 0; j < 16; ++j) {
      float4 h = xb[(baseHi + j) * 32];
      float4 l = xb[(baseLo + j) * 32];
      D = f4add(D, f4sub(h, l));
    }
  }
  red[tl][f4] = D;
  __syncthreads();
  #pragma unroll
  for (int k = 0; k < 7; ++k)
    if (k < tl) A = f4add(A, red[k][f4]);   // exclusive prefix -> A(t0+16*tl)

  const float invW = 1.0f / (float)W;
  const int tbase = t0 + 16 * tl;
  float4* ob = reinterpret_cast<float4*>(out + ((size_t)b * NOUT + tbase) * NF) + f4;

  #pragma unroll
  for (int i = 0; i < 16; ++i) {
    ob[i * 32] = make_float4(A.x * invW, A.y * invW, A.z * invW, A.w * invW);
    if (i < 15) {  // last update dead; also avoids reading x[.., 8192]
      float4 h = xb[(tbase + i + W) * 32];
      float4 l = xb[(tbase + i) * 32];
      A = f4add(A, f4sub(h, l));
    }
  }
}

extern "C" void kernel_launch(void* const* d_in, const int* in_sizes, int n_in,
                              void* d_out, int out_size, void* d_ws, size_t ws_size,
                              hipStream_t stream) {
  const float* x       = (const float*)d_in[0];
  const int*   lengths = (const int*)d_in[1];
  float*       S       = (float*)d_ws;      // NB*NSEG*NF floats = 1 MB
  float*       out     = (float*)d_out;

  hipLaunchKernelGGL(seg_sums, dim3(NB * NSEG), dim3(256), 0, stream,
                     x, lengths, S);
  hipLaunchKernelGGL(window_avg, dim3(NB * NCHUNK), dim3(256), 0, stream,
                     x, lengths, S, out);
}